// Round 8
// baseline (355.846 us; speedup 1.0000x reference)
//
#include <hip/hip_runtime.h>

// NormalizeBoardToPerspectiveLayer: per 20x20 board, normalize pids so the
// perspective player becomes 0, then rot90^k (counter-clockwise) where k =
// first corner (TL,TR,BR,BL) whose normalized value == 0. Algebraic
// simplification: normalized corner == 0  <=>  raw corner value == pid
// (empties are -1 and can never match), so k comes from RAW corners and we
// need only one barrier.
//
// Memory-bound: 1600B read + 1600B write per board (~419 MB total @ B=128K).
// Strategy: stage the RAW board in LDS (pitch 21: gcd(21,32)=1 so the
// column-wise k=1/3 gathers cycle all 32 banks), coalesced float4 on both
// global sides, normalize during the gather pass.

#define BOARDS_PER_BLOCK 8
#define THREADS 256
#define PITCH 21
#define BOARD_LDS (20 * PITCH)   // 420 floats per board

__global__ __launch_bounds__(THREADS) void normalize_rotate_kernel(
    const float* __restrict__ gboard,   // [B, 400]
    const int*   __restrict__ gpid,     // [B]
    float*       __restrict__ gout,     // [B, 400]
    int n_boards)
{
    __shared__ float lds[BOARDS_PER_BLOCK * BOARD_LDS];
    __shared__ int   lds_k[BOARDS_PER_BLOCK];
    __shared__ int   lds_addn[BOARDS_PER_BLOCK];

    const int t = threadIdx.x;
    const int board0 = blockIdx.x * BOARDS_PER_BLOCK;
    const int nb = min(BOARDS_PER_BLOCK, n_boards - board0);
    const int nchunks = nb * 100;                  // float4 chunks this block

    const float* gin = gboard + (size_t)board0 * 400;
    float*       go  = gout   + (size_t)board0 * 400;

    // --- per-board k and normalization addend ------------------------------
    if (t < nb) {
        const float* bp = gin + t * 400;
        const int pid = gpid[board0 + t];
        const float p = (float)pid;
        const float tl = bp[0], tr = bp[19], br = bp[399], bl = bp[380];
        int k = 0;
        if      (tl == p) k = 0;
        else if (tr == p) k = 1;
        else if (br == p) k = 2;
        else if (bl == p) k = 3;
        lds_k[t]    = k;
        lds_addn[t] = 4 - pid;
    }

    // --- stage raw board: coalesced float4 global reads --------------------
    for (int ch = t; ch < nchunks; ch += THREADS) {
        const int b  = ch / 100;
        const int cl = ch - b * 100;
        const float4 v = *reinterpret_cast<const float4*>(gin + ch * 4);
        const int r = cl / 5;
        const int c = (cl - r * 5) * 4;
        const int base = b * BOARD_LDS + r * PITCH + c;
        lds[base + 0] = v.x;
        lds[base + 1] = v.y;
        lds[base + 2] = v.z;
        lds[base + 3] = v.w;
    }

    __syncthreads();

    // --- gather rotated + normalize + coalesced float4 writes --------------
    for (int ch = t; ch < nchunks; ch += THREADS) {
        const int b  = ch / 100;
        const int cl = ch - b * 100;
        const int r = cl / 5;
        const int c = (cl - r * 5) * 4;
        const int k    = lds_k[b];
        const int addn = lds_addn[b];
        const int bb   = b * BOARD_LDS;

        float4 o;
        #pragma unroll
        for (int i = 0; i < 4; ++i) {
            const int ci = c + i;
            // source (rr,cc) for out[r][ci] under rot90^k, branchless
            const int r2 = (k & 2) ? (19 - r)  : r;
            const int c2 = (k & 2) ? (19 - ci) : ci;
            const int rr = (k & 1) ? c2        : r2;
            const int cc = (k & 1) ? (19 - r2) : c2;
            const float v = lds[bb + rr * PITCH + cc];
            ((float*)&o)[i] = (v < -0.5f) ? -1.0f : (float)(((int)v + addn) & 3);
        }
        *reinterpret_cast<float4*>(go + ch * 4) = o;
    }
}

extern "C" void kernel_launch(void* const* d_in, const int* in_sizes, int n_in,
                              void* d_out, int out_size, void* d_ws, size_t ws_size,
                              hipStream_t stream) {
    const float* board = (const float*)d_in[0];
    const int*   pid   = (const int*)d_in[1];
    float*       out   = (float*)d_out;

    const int n_boards = in_sizes[1];    // B (perspective_pid element count)
    const int blocks = (n_boards + BOARDS_PER_BLOCK - 1) / BOARDS_PER_BLOCK;

    normalize_rotate_kernel<<<blocks, THREADS, 0, stream>>>(board, pid, out, n_boards);
}